// Round 1
// 446.059 us; speedup vs baseline: 1.0099x; 1.0099x over previous
//
#include <hip/hip_runtime.h>

// Vectorized 256 MB copy: one float4 (16 B) per thread, fully coalesced
// (m13-pattern, measured 6.29 TB/s on MI355X). Loads of x are non-temporal:
// x is read exactly once, so keep it out of L3 and leave the Infinity Cache
// to hold the freshly written `out` lines — the scatter's RMW then hits L3.
typedef float __attribute__((ext_vector_type(4))) f32x4;

__global__ __launch_bounds__(256) void fi_copy_kernel(const f32x4* __restrict__ src,
                                                      f32x4* __restrict__ dst,
                                                      int n4) {
    int i = blockIdx.x * blockDim.x + threadIdx.x;
    if (i < n4) {
        f32x4 v = __builtin_nontemporal_load(src + i);
        dst[i] = v;   // normal (cached) store: out stays L3-resident for the scatter
    }
}

// Scatter: out[idx[i]] = vals[i]. Indices are unique (randperm prefix), so
// plain stores are race-free. 4 faults per thread: vectorized int4/float4
// loads of idx/vals, 4 scattered 4 B stores. nf = 671,089 = 4*167,772 + 1;
// the tail (1 element) is handled by thread 0.
__global__ __launch_bounds__(256) void fi_scatter_kernel(const float* __restrict__ vals,
                                                         const int* __restrict__ idx,
                                                         float* __restrict__ out,
                                                         int nq,   // nf / 4
                                                         int nf) {
    int i = blockIdx.x * blockDim.x + threadIdx.x;
    if (i < nq) {
        int4   id = ((const int4*)idx)[i];
        float4 v  = ((const float4*)vals)[i];
        out[id.x] = v.x;
        out[id.y] = v.y;
        out[id.z] = v.z;
        out[id.w] = v.w;
    }
    if (i == 0) {
        for (int k = nq * 4; k < nf; ++k) out[idx[k]] = vals[k];
    }
}

extern "C" void kernel_launch(void* const* d_in, const int* in_sizes, int n_in,
                              void* d_out, int out_size, void* d_ws, size_t ws_size,
                              hipStream_t stream) {
    const float* x    = (const float*)d_in[0];
    const float* vals = (const float*)d_in[1];
    const int*   idx  = (const int*)d_in[2];
    float* out = (float*)d_out;

    const int numel = in_sizes[0];   // 67,108,864 (divisible by 4)
    const int nf    = in_sizes[1];   // 671,089

    // 1) Bulk copy x -> out with float4 vector loads/stores (nt loads).
    const int n4     = numel / 4;                   // 16,777,216
    const int cblock = 256;
    const int cgrid  = (n4 + cblock - 1) / cblock;  // 65,536 blocks
    fi_copy_kernel<<<cgrid, cblock, 0, stream>>>((const f32x4*)x, (f32x4*)out, n4);

    // 2) Scatter the fault values over the copy (stream-ordered after the copy).
    const int nq     = nf / 4;                      // 167,772
    const int sblock = 256;
    const int sgrid  = (nq + sblock - 1) / sblock;  // 656 blocks
    fi_scatter_kernel<<<sgrid, sblock, 0, stream>>>(vals, idx, out, nq, nf);
}

// Round 3
// 444.377 us; speedup vs baseline: 1.0138x; 1.0038x over previous
//
#include <hip/hip_runtime.h>

// Vectorized 256 MB copy: one float4 (16 B) per thread, fully coalesced
// (m13-pattern, measured 6.29 TB/s on MI355X). Loads of x are non-temporal:
// x is read exactly once, so keep it out of L3 and leave the Infinity Cache
// to hold the freshly written `out` lines — the scatter's RMW then hits L3.
// NOTE (R2): hipMemcpyAsync D2D crashes this harness's graph capture (blit/
// SDMA path) — the copy MUST stay a hand-rolled kernel.
typedef float __attribute__((ext_vector_type(4))) f32x4;

__global__ __launch_bounds__(256) void fi_copy_kernel(const f32x4* __restrict__ src,
                                                      f32x4* __restrict__ dst,
                                                      int n4) {
    int i = blockIdx.x * blockDim.x + threadIdx.x;
    if (i < n4) {
        f32x4 v = __builtin_nontemporal_load(src + i);
        dst[i] = v;   // normal (cached) store: out stays L3-resident for the scatter
    }
}

// Scatter: out[idx[i]] = vals[i]. Indices are unique (randperm prefix), so
// plain stores are race-free. 4 faults per thread: vectorized int4/float4
// loads of idx/vals, 4 scattered 4 B stores. nf = 671,089 = 4*167,772 + 1;
// the tail (1 element) is handled by thread 0.
__global__ __launch_bounds__(256) void fi_scatter_kernel(const float* __restrict__ vals,
                                                         const int* __restrict__ idx,
                                                         float* __restrict__ out,
                                                         int nq,   // nf / 4
                                                         int nf) {
    int i = blockIdx.x * blockDim.x + threadIdx.x;
    if (i < nq) {
        int4   id = ((const int4*)idx)[i];
        float4 v  = ((const float4*)vals)[i];
        out[id.x] = v.x;
        out[id.y] = v.y;
        out[id.z] = v.z;
        out[id.w] = v.w;
    }
    if (i == 0) {
        for (int k = nq * 4; k < nf; ++k) out[idx[k]] = vals[k];
    }
}

extern "C" void kernel_launch(void* const* d_in, const int* in_sizes, int n_in,
                              void* d_out, int out_size, void* d_ws, size_t ws_size,
                              hipStream_t stream) {
    const float* x    = (const float*)d_in[0];
    const float* vals = (const float*)d_in[1];
    const int*   idx  = (const int*)d_in[2];
    float* out = (float*)d_out;

    const int numel = in_sizes[0];   // 67,108,864 (divisible by 4)
    const int nf    = in_sizes[1];   // 671,089

    // 1) Bulk copy x -> out with float4 vector loads/stores (nt loads).
    const int n4     = numel / 4;                   // 16,777,216
    const int cblock = 256;
    const int cgrid  = (n4 + cblock - 1) / cblock;  // 65,536 blocks
    fi_copy_kernel<<<cgrid, cblock, 0, stream>>>((const f32x4*)x, (f32x4*)out, n4);

    // 2) Scatter the fault values over the copy (stream-ordered after the copy).
    const int nq     = nf / 4;                      // 167,772
    const int sblock = 256;
    const int sgrid  = (nq + sblock - 1) / sblock;  // 656 blocks
    fi_scatter_kernel<<<sgrid, sblock, 0, stream>>>(vals, idx, out, nq, nf);
}